// Round 7
// baseline (167.693 us; speedup 1.0000x reference)
//
#include <hip/hip_runtime.h>
#include <hip/hip_bf16.h>

#define L_SEQ 2048
#define DM 512

typedef short bf16x8 __attribute__((ext_vector_type(8)));
typedef float f32x4 __attribute__((ext_vector_type(4)));
typedef float f32x16 __attribute__((ext_vector_type(16)));
typedef unsigned short u16;
typedef u16 u16x8 __attribute__((ext_vector_type(8)));
typedef u16 u16x4 __attribute__((ext_vector_type(4)));

__device__ __forceinline__ u16 f2bf(float f) {
    unsigned int u = __float_as_uint(f);
    u += 0x7fffu + ((u >> 16) & 1u);
    return (u16)(u >> 16);
}

__device__ __forceinline__ unsigned int pk_bf16(float a, float b) {
    __hip_bfloat162 h = __float22bfloat162_rn(float2{a, b});
    unsigned int u;
    __builtin_memcpy(&u, &h, 4);
    return u;
}

__device__ __forceinline__ void lds_load16(const void* g, void* l) {
    __builtin_amdgcn_global_load_lds(
        (const __attribute__((address_space(1))) unsigned int*)g,
        (__attribute__((address_space(3))) unsigned int*)l,
        16, 0, 0);
}

__device__ __forceinline__ f32x16 zero16() {
    f32x16 z;
#pragma unroll
    for (int i = 0; i < 16; ++i) z[i] = 0.f;
    return z;
}

// ---------------- prep: x transpose+cast (z<8) and weight casts (z==8) ----------------
__global__ void prep(const float* __restrict__ x1, const float* __restrict__ x2,
                     const float* __restrict__ Wq, const float* __restrict__ Wk,
                     const float* __restrict__ Wv,
                     u16* __restrict__ xT, u16* __restrict__ Wall) {
    __shared__ u16 t[128 * 136];
    const int tid = threadIdx.x;
    if (blockIdx.z == 8) {
        int gid = (blockIdx.y * 16 + blockIdx.x) * 256 + tid;
#pragma unroll
        for (int p = 0; p < 12; ++p) {
            int i = p * 16384 + gid;
            int which = i >> 16, j = i & 65535;
            const float* src = (which == 0) ? Wq : (which == 1 ? Wk : Wv);
            float4 v = ((const float4*)src)[j];
            ushort4 o;
            o.x = f2bf(v.x); o.y = f2bf(v.y); o.z = f2bf(v.z); o.w = f2bf(v.w);
            ((ushort4*)Wall)[i] = o;
        }
        return;
    }
    const int z = blockIdx.z, b = z & 3, c0 = blockIdx.y * 128, l0 = blockIdx.x * 128;
    const float* src = (z < 4) ? x1 : x2;
    u16* dbase = xT + (size_t)(z >> 2) * 4194304;
    const float* sp = src + ((size_t)b * DM + c0) * L_SEQ + l0;
#pragma unroll
    for (int p = 0; p < 16; ++p) {
        int id = p * 256 + tid;
        int ci = id >> 5, f4 = id & 31;
        float4 v = *(const float4*)(sp + (size_t)ci * L_SEQ + f4 * 4);
        u16x4 o;
        o[0] = f2bf(v.x); o[1] = f2bf(v.y); o[2] = f2bf(v.z); o[3] = f2bf(v.w);
        *(u16x4*)(t + ci * 136 + f4 * 4) = o;
    }
    __syncthreads();
    u16* dp = dbase + ((size_t)b * L_SEQ + l0) * DM + c0;
#pragma unroll
    for (int p = 0; p < 8; ++p) {
        int id = p * 256 + tid;
        int lj = id >> 4, c8 = id & 15;
        u16x8 o;
#pragma unroll
        for (int i = 0; i < 8; ++i) o[i] = t[(c8 * 8 + i) * 136 + lj];
        *(u16x8*)(dp + (size_t)lj * DM + c8 * 8) = o;
    }
}

// ---------------- fused QKV projection GEMM: ping-pong staging, R3 epilogue ----------------
__launch_bounds__(256, 3)
__global__ void proj_gemm(const u16* __restrict__ x1T, const u16* __restrict__ x2T,
                          const u16* __restrict__ Wall,
                          const float* __restrict__ bq, const float* __restrict__ bk,
                          const float* __restrict__ bv,
                          u16* __restrict__ Qo, u16* __restrict__ Ko, u16* __restrict__ Vto) {
    __shared__ __align__(16) char smem[34816];
    // abuf0 @0, bbuf0 @8K, abuf1 @16K, bbuf1 @24K
    const int by = blockIdx.y;
    const int b = by / 3, pj = by % 3;
    const int m0 = (blockIdx.x >> 2) * 128, n0 = (blockIdx.x & 3) * 128;
    const u16* xT = (pj == 0) ? x1T : x2T;
    const u16* W = Wall + (size_t)pj * 262144;
    const float* bias = (pj == 0) ? bq : (pj == 1 ? bk : bv);
    const float scale = (pj == 0) ? 0.18033688011112042f : 1.0f; // (1/8)*log2(e)

    const int tid = threadIdx.x;
    const int w = tid >> 6, lane = tid & 63;
    const int lm = lane & 15, lq = lane >> 4;
    const int wrow = (w & 1) * 64, wcol = (w >> 1) * 64;

    const u16* gA[2]; const u16* gB[2];
    int adst[2];
#pragma unroll
    for (int j = 0; j < 2; ++j) {
        int s = j * 256 + tid;
        int r = s >> 2, c = s & 3, cc = c ^ (r & 3);
        gA[j] = xT + ((size_t)b * L_SEQ + m0 + r) * DM + cc * 8;
        gB[j] = W + (size_t)(n0 + r) * DM + cc * 8;
        adst[j] = (j * 256 + w * 64) * 8;
    }

    f32x4 acc[4][4];
#pragma unroll
    for (int mt = 0; mt < 4; ++mt)
#pragma unroll
        for (int nt = 0; nt < 4; ++nt) acc[mt][nt] = (f32x4){0.f, 0.f, 0.f, 0.f};

#pragma unroll
    for (int j = 0; j < 2; ++j) {
        lds_load16(gA[j], (u16*)smem + adst[j]);
        lds_load16(gB[j], (u16*)(smem + 8192) + adst[j]);
    }

    for (int kt = 0; kt < 16; ++kt) {
        __syncthreads();
        if (kt < 15) {
            int nb = (kt + 1) & 1;
#pragma unroll
            for (int j = 0; j < 2; ++j) {
                lds_load16(gA[j] + (kt + 1) * 32, (u16*)(smem + nb * 16384) + adst[j]);
                lds_load16(gB[j] + (kt + 1) * 32, (u16*)(smem + 8192 + nb * 16384) + adst[j]);
            }
        }
        const u16* a_lds = (const u16*)(smem + (kt & 1) * 16384);
        const u16* b_lds = (const u16*)(smem + 8192 + (kt & 1) * 16384);
        bf16x8 af[4], bfr[4];
#pragma unroll
        for (int mt = 0; mt < 4; ++mt) {
            int r = wrow + mt * 16 + lm;
            af[mt] = *(const bf16x8*)(a_lds + r * 32 + (lq ^ (r & 3)) * 8);
        }
#pragma unroll
        for (int nt = 0; nt < 4; ++nt) {
            int r = wcol + nt * 16 + lm;
            bfr[nt] = *(const bf16x8*)(b_lds + r * 32 + (lq ^ (r & 3)) * 8);
        }
#pragma unroll
        for (int mt = 0; mt < 4; ++mt)
#pragma unroll
            for (int nt = 0; nt < 4; ++nt)
                acc[mt][nt] = __builtin_amdgcn_mfma_f32_16x16x32_bf16(af[mt], bfr[nt], acc[mt][nt], 0, 0, 0);
    }

    float bvv[4];
#pragma unroll
    for (int nt = 0; nt < 4; ++nt) bvv[nt] = bias[n0 + wcol + nt * 16 + lm];

    if (pj < 2) {
        u16* dst = (pj == 0) ? Qo : Ko;
#pragma unroll
        for (int mt = 0; mt < 4; ++mt)
#pragma unroll
            for (int nt = 0; nt < 4; ++nt) {
                int col = n0 + wcol + nt * 16 + lm;
#pragma unroll
                for (int r = 0; r < 4; ++r) {
                    int row = m0 + wrow + mt * 16 + lq * 4 + r;
                    dst[((size_t)b * L_SEQ + row) * DM + col] = f2bf((acc[mt][nt][r] + bvv[nt]) * scale);
                }
            }
    } else {
        __syncthreads();
        u16* epi = (u16*)smem;
#pragma unroll
        for (int mt = 0; mt < 4; ++mt)
#pragma unroll
            for (int nt = 0; nt < 4; ++nt) {
                int colL = wcol + nt * 16 + lm;
                int row0 = wrow + mt * 16 + lq * 4;
                u16x4 tv;
#pragma unroll
                for (int r = 0; r < 4; ++r) tv[r] = f2bf(acc[mt][nt][r] + bvv[nt]);
                *(u16x4*)(epi + colL * 136 + row0) = tv;
            }
        __syncthreads();
#pragma unroll
        for (int p = 0; p < 8; ++p) {
            int id = p * 256 + tid;
            int rr = id >> 4, ch = id & 15;
            u16x8 vv = *(const u16x8*)(epi + rr * 136 + ch * 8);
            *(u16x8*)(Vto + ((size_t)b * DM + n0 + rr) * L_SEQ + m0 + ch * 8) = vv;
        }
    }
}

// ---------------- flash attention: key-split wave pairs, P in registers ----------------
// 512 blocks x 512 threads (8 waves). BM=128 q: wave (qg=w&3, hk=w>>2) owns q-rows
// [32qg,32qg+32) and key-half hk of each BN=64 tile. P exchanged via shfl_xor(32).
__launch_bounds__(512, 4)
__global__ void attn(const u16* __restrict__ Q, const u16* __restrict__ K,
                     const u16* __restrict__ Vt, float* __restrict__ out) {
    __shared__ __align__(16) char smem[34816];
    // kbuf0 @0, kbuf1 @8K, vbuf0 @16K, vbuf1 @24K; l @33792 (2x128 f32)
    // o_lds overlay @0: [64 d][132 f32] = 33792 B (kv dead in epilogue)
    float* l_lds = (float*)(smem + 33792);
    float* o_lds = (float*)smem;

    const int i = blockIdx.x;
    const int g = i & 7, r_ = i >> 3;
    const int qb = r_ & 15, bh = ((r_ >> 4) << 3) + g;
    const int h_ = bh >> 2, b = bh & 3;

    const int tid = threadIdx.x, w = tid >> 6, lane = tid & 63;
    const int q0 = qb * 128;
    const int lm32 = lane & 31, hi = lane >> 5;
    const int qg = w & 3, hk = w >> 2;
    const int qrow = qg * 32 + lm32;

    const u16* Qb = Q + ((size_t)b * L_SEQ + q0) * DM + h_ * 64;
    const u16* Kb = K + (size_t)b * L_SEQ * DM + h_ * 64;
    const u16* Vb = Vt + ((size_t)b * DM + h_ * 64) * L_SEQ;

    // K/V staging: 8KB tile = 512 slots of 16B, 1 per thread
    const u16 *gK, *gV;
    int soff;
    {
        int r = tid >> 3, c = tid & 7, cc = c ^ (r & 7);
        gK = Kb + (size_t)r * DM + cc * 8;
        gV = Vb + (size_t)r * L_SEQ + cc * 8;   // r = d row for V
        soff = (w * 64) * 8;
    }

    // stage Q (128x64 = 16KB) through kbuf0+kbuf1
#pragma unroll
    for (int j = 0; j < 2; ++j) {
        int s = j * 512 + tid;
        int r = s >> 3, c = s & 7, cc = c ^ (r & 7);
        lds_load16(Qb + (size_t)r * DM + cc * 8, (u16*)smem + (j * 512 + w * 64) * 8);
    }
    __syncthreads();
    bf16x8 qf[4];
#pragma unroll
    for (int c = 0; c < 4; ++c) {
        int slot = (2 * c + hi) ^ (qrow & 7);
        qf[c] = *(const bf16x8*)((const u16*)smem + qrow * 64 + slot * 8);
    }
    __syncthreads();   // Q reads done; kbufs reusable

    float l_part = 0.f;
    f32x16 o_acc[2];
    o_acc[0] = zero16(); o_acc[1] = zero16();

    // prologue: tile 0
    lds_load16(gK, (u16*)smem + soff);
    lds_load16(gV, (u16*)(smem + 16384) + soff);

    const int rk = hk * 32 + lm32;   // this lane's key row within BN tile

    for (int kt = 0; kt < 32; ++kt) {
        __syncthreads();
        if (kt < 31) {
            int nb = (kt + 1) & 1;
            lds_load16(gK + (size_t)(kt + 1) * 64 * DM, (u16*)(smem + nb * 8192) + soff);
            lds_load16(gV + (kt + 1) * 64, (u16*)(smem + 16384 + nb * 8192) + soff);
        }
        const u16* kl = (const u16*)(smem + (kt & 1) * 8192);
        const u16* vl = (const u16*)(smem + 16384 + (kt & 1) * 8192);

        // S^T = K Q^T over this wave's 32-key half: A=K rows, B=Q (n=q)
        f32x16 s = zero16();
#pragma unroll
        for (int c = 0; c < 4; ++c) {
            int slot = (2 * c + hi) ^ (rk & 7);
            bf16x8 af = *(const bf16x8*)(kl + rk * 64 + slot * 8);
            s = __builtin_amdgcn_mfma_f32_32x32x16_bf16(af, qf[c], s, 0, 0, 0);
        }
        // softmax numerators; keep P packed in registers
        // D: col=q, row(local key) = (reg&3)+8*(reg>>2)+4*hi
        uint2 pw[4];
#pragma unroll
        for (int g2 = 0; g2 < 4; ++g2) {
            float p0 = __builtin_amdgcn_exp2f(s[4 * g2 + 0]);
            float p1 = __builtin_amdgcn_exp2f(s[4 * g2 + 1]);
            float p2 = __builtin_amdgcn_exp2f(s[4 * g2 + 2]);
            float p3 = __builtin_amdgcn_exp2f(s[4 * g2 + 3]);
            l_part += (p0 + p1) + (p2 + p3);
            pw[g2].x = pk_bf16(p0, p1);
            pw[g2].y = pk_bf16(p2, p3);
        }

        // O += P V; A-frags assembled by lane^32 exchange (same q, other 4-key groups)
#pragma unroll
        for (int c2 = 0; c2 < 2; ++c2) {
            uint2 pa = pw[2 * c2], pb = pw[2 * c2 + 1];
            uint2 kep, snd;
            if (hi) { kep = pb; snd = pa; } else { kep = pa; snd = pb; }
            uint2 rcv;
            rcv.x = __shfl_xor(snd.x, 32);
            rcv.y = __shfl_xor(snd.y, 32);
            uint4 pu;
            if (hi) { pu.x = rcv.x; pu.y = rcv.y; pu.z = kep.x; pu.w = kep.y; }
            else    { pu.x = kep.x; pu.y = kep.y; pu.z = rcv.x; pu.w = rcv.y; }
            bf16x8 pf;
            __builtin_memcpy(&pf, &pu, 16);
#pragma unroll
            for (int dt = 0; dt < 2; ++dt) {
                int d = dt * 32 + lm32;
                int kc = hk * 4 + c2 * 2 + hi;
                bf16x8 vf = *(const bf16x8*)(vl + d * 64 + (kc ^ (d & 7)) * 8);
                o_acc[dt] = __builtin_amdgcn_mfma_f32_32x32x16_bf16(pf, vf, o_acc[dt], 0, 0, 0);
            }
        }
    }

    // per-(q, half) row sum: lane + partner cover the 32 keys of this half
    l_part += __shfl_xor(l_part, 32);

    __syncthreads();   // kv bufs dead; overlay o_lds
    if (hi == 0) l_lds[hk * 128 + qrow] = l_part;
    // O partial merge: hk=0 writes, hk=1 accumulates
    // o_acc D: col=lane&31 -> d = dt*32+lm32; regs = q rows qg*32 + 8*g2 + 4*hi + r
    if (hk == 0) {
#pragma unroll
        for (int dt = 0; dt < 2; ++dt) {
            int d = dt * 32 + lm32;
#pragma unroll
            for (int g2 = 0; g2 < 4; ++g2) {
                f32x4 vq;
#pragma unroll
                for (int r = 0; r < 4; ++r) vq[r] = o_acc[dt][4 * g2 + r];
                *(f32x4*)(o_lds + d * 132 + qg * 32 + 8 * g2 + 4 * hi) = vq;
            }
        }
    }
    __syncthreads();
    if (hk == 1) {
#pragma unroll
        for (int dt = 0; dt < 2; ++dt) {
            int d = dt * 32 + lm32;
#pragma unroll
            for (int g2 = 0; g2 < 4; ++g2) {
                float* ad = o_lds + d * 132 + qg * 32 + 8 * g2 + 4 * hi;
                f32x4 cur = *(f32x4*)ad;
#pragma unroll
                for (int r = 0; r < 4; ++r) cur[r] += o_acc[dt][4 * g2 + r];
                *(f32x4*)ad = cur;
            }
        }
    }
    __syncthreads();
    float* ob = out + ((size_t)b * DM + h_ * 64) * L_SEQ + q0;
#pragma unroll
    for (int p = 0; p < 4; ++p) {
        int id = p * 512 + tid;
        int d = id >> 5, rc = id & 31;
        f32x4 vv = *(const f32x4*)(o_lds + d * 132 + rc * 4);
        f32x4 la = *(const f32x4*)(l_lds + rc * 4);
        f32x4 lb = *(const f32x4*)(l_lds + 128 + rc * 4);
#pragma unroll
        for (int j = 0; j < 4; ++j) vv[j] *= 1.0f / (la[j] + lb[j]);
        *(f32x4*)(ob + (size_t)d * L_SEQ + rc * 4) = vv;
    }
}

extern "C" void kernel_launch(void* const* d_in, const int* in_sizes, int n_in,
                              void* d_out, int out_size, void* d_ws, size_t ws_size,
                              hipStream_t stream) {
    const float* x1 = (const float*)d_in[0];
    const float* x2 = (const float*)d_in[1];
    const float* Wq = (const float*)d_in[2];
    const float* bq = (const float*)d_in[3];
    const float* Wk = (const float*)d_in[4];
    const float* bk = (const float*)d_in[5];
    const float* Wv = (const float*)d_in[6];
    const float* bv = (const float*)d_in[7];
    float* out = (float*)d_out;

    char* ws = (char*)d_ws;
    u16* x1T = (u16*)(ws);
    u16* x2T = (u16*)(ws + 8388608);
    u16* Wall = (u16*)(ws + 16777216);
    u16* Qb  = (u16*)(ws + 18350080);
    u16* Kb  = (u16*)(ws + 26738688);
    u16* Vtb = (u16*)(ws + 35127296);

    prep<<<dim3(16, 4, 9), 256, 0, stream>>>(x1, x2, Wq, Wk, Wv, x1T, Wall);
    proj_gemm<<<dim3(64, 12), 256, 0, stream>>>(x1T, x2T, Wall, bq, bk, bv, Qb, Kb, Vtb);
    attn<<<512, 512, 0, stream>>>(Qb, Kb, Vtb, out);
}

// Round 8
// 163.258 us; speedup vs baseline: 1.0272x; 1.0272x over previous
//
#include <hip/hip_runtime.h>
#include <hip/hip_bf16.h>

#define L_SEQ 2048
#define DM 512

typedef short bf16x8 __attribute__((ext_vector_type(8)));
typedef float f32x4 __attribute__((ext_vector_type(4)));
typedef float f32x16 __attribute__((ext_vector_type(16)));
typedef unsigned short u16;
typedef u16 u16x8 __attribute__((ext_vector_type(8)));
typedef u16 u16x4 __attribute__((ext_vector_type(4)));

__device__ __forceinline__ u16 f2bf(float f) {
    unsigned int u = __float_as_uint(f);
    u += 0x7fffu + ((u >> 16) & 1u);
    return (u16)(u >> 16);
}

__device__ __forceinline__ unsigned int pk_bf16(float a, float b) {
    __hip_bfloat162 h = __float22bfloat162_rn(float2{a, b});
    unsigned int u;
    __builtin_memcpy(&u, &h, 4);
    return u;
}

__device__ __forceinline__ void lds_load16(const void* g, void* l) {
    __builtin_amdgcn_global_load_lds(
        (const __attribute__((address_space(1))) unsigned int*)g,
        (__attribute__((address_space(3))) unsigned int*)l,
        16, 0, 0);
}

__device__ __forceinline__ f32x16 zero16() {
    f32x16 z;
#pragma unroll
    for (int i = 0; i < 16; ++i) z[i] = 0.f;
    return z;
}

// ---------------- prep: x transpose+cast (z<8) and weight casts (z==8) ----------------
__global__ void prep(const float* __restrict__ x1, const float* __restrict__ x2,
                     const float* __restrict__ Wq, const float* __restrict__ Wk,
                     const float* __restrict__ Wv,
                     u16* __restrict__ xT, u16* __restrict__ Wall) {
    __shared__ u16 t[128 * 136];
    const int tid = threadIdx.x;
    if (blockIdx.z == 8) {
        int gid = (blockIdx.y * 16 + blockIdx.x) * 256 + tid;
#pragma unroll
        for (int p = 0; p < 12; ++p) {
            int i = p * 16384 + gid;
            int which = i >> 16, j = i & 65535;
            const float* src = (which == 0) ? Wq : (which == 1 ? Wk : Wv);
            float4 v = ((const float4*)src)[j];
            ushort4 o;
            o.x = f2bf(v.x); o.y = f2bf(v.y); o.z = f2bf(v.z); o.w = f2bf(v.w);
            ((ushort4*)Wall)[i] = o;
        }
        return;
    }
    const int z = blockIdx.z, b = z & 3, c0 = blockIdx.y * 128, l0 = blockIdx.x * 128;
    const float* src = (z < 4) ? x1 : x2;
    u16* dbase = xT + (size_t)(z >> 2) * 4194304;
    const float* sp = src + ((size_t)b * DM + c0) * L_SEQ + l0;
#pragma unroll
    for (int p = 0; p < 16; ++p) {
        int id = p * 256 + tid;
        int ci = id >> 5, f4 = id & 31;
        float4 v = *(const float4*)(sp + (size_t)ci * L_SEQ + f4 * 4);
        u16x4 o;
        o[0] = f2bf(v.x); o[1] = f2bf(v.y); o[2] = f2bf(v.z); o[3] = f2bf(v.w);
        *(u16x4*)(t + ci * 136 + f4 * 4) = o;
    }
    __syncthreads();
    u16* dp = dbase + ((size_t)b * L_SEQ + l0) * DM + c0;
#pragma unroll
    for (int p = 0; p < 8; ++p) {
        int id = p * 256 + tid;
        int lj = id >> 4, c8 = id & 15;
        u16x8 o;
#pragma unroll
        for (int i = 0; i < 8; ++i) o[i] = t[(c8 * 8 + i) * 136 + lj];
        *(u16x8*)(dp + (size_t)lj * DM + c8 * 8) = o;
    }
}

// ---------------- fused QKV projection GEMM: ping-pong, unroll-2, const LDS bases ----------------
#define PROJ_BODY(AB, BB, NAB, NBB, DO_STAGE)                                   \
    {                                                                           \
        __syncthreads();                                                        \
        if (DO_STAGE) {                                                         \
            lds_load16(pA0, smem + (NAB) + sd0);                                \
            lds_load16(pA1, smem + (NAB) + sd1);                                \
            lds_load16(pB0, smem + (NBB) + sd0);                                \
            lds_load16(pB1, smem + (NBB) + sd1);                                \
            pA0 += 32; pA1 += 32; pB0 += 32; pB1 += 32;                         \
        }                                                                       \
        bf16x8 af[4], bfr[4];                                                   \
        _Pragma("unroll")                                                       \
        for (int mt = 0; mt < 4; ++mt)                                          \
            af[mt] = *(const bf16x8*)(smem + (AB) + aoffb[mt]);                 \
        _Pragma("unroll")                                                       \
        for (int nt = 0; nt < 4; ++nt)                                          \
            bfr[nt] = *(const bf16x8*)(smem + (BB) + boffb[nt]);                \
        _Pragma("unroll")                                                       \
        for (int mt = 0; mt < 4; ++mt)                                          \
            _Pragma("unroll")                                                   \
            for (int nt = 0; nt < 4; ++nt)                                      \
                acc[mt][nt] = __builtin_amdgcn_mfma_f32_16x16x32_bf16(          \
                    af[mt], bfr[nt], acc[mt][nt], 0, 0, 0);                     \
    }

__launch_bounds__(256, 3)
__global__ void proj_gemm(const u16* __restrict__ x1T, const u16* __restrict__ x2T,
                          const u16* __restrict__ Wall,
                          const float* __restrict__ bq, const float* __restrict__ bk,
                          const float* __restrict__ bv,
                          u16* __restrict__ Qo, u16* __restrict__ Ko, u16* __restrict__ Vto) {
    __shared__ __align__(16) char smem[34816];
    // A0 @0, B0 @8192, A1 @16384, B1 @24576
    const int by = blockIdx.y;
    const int b = by / 3, pj = by % 3;
    const int m0 = (blockIdx.x >> 2) * 128, n0 = (blockIdx.x & 3) * 128;
    const u16* xT = (pj == 0) ? x1T : x2T;
    const u16* W = Wall + (size_t)pj * 262144;
    const float* bias = (pj == 0) ? bq : (pj == 1 ? bk : bv);
    const float scale = (pj == 0) ? 0.18033688011112042f : 1.0f; // (1/8)*log2(e)

    const int tid = threadIdx.x;
    const int w = tid >> 6, lane = tid & 63;
    const int lm = lane & 15, lq = lane >> 4;
    const int wrow = (w & 1) * 64, wcol = (w >> 1) * 64;

    // staging sources (advanced incrementally); LDS dests as byte offsets
    const u16 *pA0, *pA1, *pB0, *pB1;
    {
        int s0 = tid, r0 = s0 >> 2, c0 = (s0 & 3) ^ (r0 & 3);
        int s1 = 256 + tid, r1 = s1 >> 2, c1 = (s1 & 3) ^ (r1 & 3);
        pA0 = xT + ((size_t)b * L_SEQ + m0 + r0) * DM + c0 * 8;
        pA1 = xT + ((size_t)b * L_SEQ + m0 + r1) * DM + c1 * 8;
        pB0 = W + (size_t)(n0 + r0) * DM + c0 * 8;
        pB1 = W + (size_t)(n0 + r1) * DM + c1 * 8;
    }
    const int sd0 = w * 1024;            // (w*64)*16 bytes
    const int sd1 = 4096 + w * 1024;

    // per-lane fragment byte offsets (loop-invariant)
    int aoffb[4], boffb[4];
#pragma unroll
    for (int mt = 0; mt < 4; ++mt) {
        int r = wrow + mt * 16 + lm;
        aoffb[mt] = r * 64 + (lq ^ (r & 3)) * 16;
    }
#pragma unroll
    for (int nt = 0; nt < 4; ++nt) {
        int r = wcol + nt * 16 + lm;
        boffb[nt] = r * 64 + (lq ^ (r & 3)) * 16;
    }

    f32x4 acc[4][4];
#pragma unroll
    for (int mt = 0; mt < 4; ++mt)
#pragma unroll
        for (int nt = 0; nt < 4; ++nt) acc[mt][nt] = (f32x4){0.f, 0.f, 0.f, 0.f};

    // prologue: tile 0 into A0/B0
    lds_load16(pA0, smem + 0 + sd0);
    lds_load16(pA1, smem + 0 + sd1);
    lds_load16(pB0, smem + 8192 + sd0);
    lds_load16(pB1, smem + 8192 + sd1);
    pA0 += 32; pA1 += 32; pB0 += 32; pB1 += 32;

    for (int kt2 = 0; kt2 < 8; ++kt2) {
        PROJ_BODY(0, 8192, 16384, 24576, true)          // compute tile 2kt2 (buf0), stage 2kt2+1
        PROJ_BODY(16384, 24576, 0, 8192, (kt2 < 7))     // compute tile 2kt2+1 (buf1), stage 2kt2+2
    }

    float bvv[4];
#pragma unroll
    for (int nt = 0; nt < 4; ++nt) bvv[nt] = bias[n0 + wcol + nt * 16 + lm];

    if (pj < 2) {
        u16* dst = (pj == 0) ? Qo : Ko;
#pragma unroll
        for (int mt = 0; mt < 4; ++mt)
#pragma unroll
            for (int nt = 0; nt < 4; ++nt) {
                int col = n0 + wcol + nt * 16 + lm;
#pragma unroll
                for (int r = 0; r < 4; ++r) {
                    int row = m0 + wrow + mt * 16 + lq * 4 + r;
                    dst[((size_t)b * L_SEQ + row) * DM + col] = f2bf((acc[mt][nt][r] + bvv[nt]) * scale);
                }
            }
    } else {
        __syncthreads();
        u16* epi = (u16*)smem;
#pragma unroll
        for (int mt = 0; mt < 4; ++mt)
#pragma unroll
            for (int nt = 0; nt < 4; ++nt) {
                int colL = wcol + nt * 16 + lm;
                int row0 = wrow + mt * 16 + lq * 4;
                u16x4 tv;
#pragma unroll
                for (int r = 0; r < 4; ++r) tv[r] = f2bf(acc[mt][nt][r] + bvv[nt]);
                *(u16x4*)(epi + colL * 136 + row0) = tv;
            }
        __syncthreads();
#pragma unroll
        for (int p = 0; p < 8; ++p) {
            int id = p * 256 + tid;
            int rr = id >> 4, ch = id & 15;
            u16x8 vv = *(const u16x8*)(epi + rr * 136 + ch * 8);
            *(u16x8*)(Vto + ((size_t)b * DM + n0 + rr) * L_SEQ + m0 + ch * 8) = vv;
        }
    }
}

// ---------------- flash attention: key-split wave pairs, unroll-2, const LDS bases ----------------
#define ATTN_BODY(KB, VB, NKB, NVB, DO_STAGE)                                   \
    {                                                                           \
        __syncthreads();                                                        \
        if (DO_STAGE) {                                                         \
            lds_load16(pKn, smem + (NKB) + sdb);                                \
            lds_load16(pVn, smem + (NVB) + sdb);                                \
            pKn += 64 * DM; pVn += 64;                                          \
        }                                                                       \
        f32x16 s = zero16();                                                    \
        _Pragma("unroll")                                                       \
        for (int c = 0; c < 4; ++c) {                                           \
            bf16x8 af = *(const bf16x8*)(smem + (KB) + koffb[c]);               \
            s = __builtin_amdgcn_mfma_f32_32x32x16_bf16(af, qf[c], s, 0, 0, 0); \
        }                                                                       \
        uint2 pw[4];                                                            \
        _Pragma("unroll")                                                       \
        for (int g2 = 0; g2 < 4; ++g2) {                                        \
            float p0 = __builtin_amdgcn_exp2f(s[4 * g2 + 0]);                   \
            float p1 = __builtin_amdgcn_exp2f(s[4 * g2 + 1]);                   \
            float p2 = __builtin_amdgcn_exp2f(s[4 * g2 + 2]);                   \
            float p3 = __builtin_amdgcn_exp2f(s[4 * g2 + 3]);                   \
            l_part += (p0 + p1) + (p2 + p3);                                    \
            pw[g2].x = pk_bf16(p0, p1);                                         \
            pw[g2].y = pk_bf16(p2, p3);                                         \
        }                                                                       \
        _Pragma("unroll")                                                       \
        for (int c2 = 0; c2 < 2; ++c2) {                                        \
            uint2 pa = pw[2 * c2], pb = pw[2 * c2 + 1];                         \
            uint2 kep, snd;                                                     \
            if (hi) { kep = pb; snd = pa; } else { kep = pa; snd = pb; }        \
            uint2 rcv;                                                          \
            rcv.x = __shfl_xor(snd.x, 32);                                      \
            rcv.y = __shfl_xor(snd.y, 32);                                      \
            uint4 pu;                                                           \
            if (hi) { pu.x = rcv.x; pu.y = rcv.y; pu.z = kep.x; pu.w = kep.y; } \
            else    { pu.x = kep.x; pu.y = kep.y; pu.z = rcv.x; pu.w = rcv.y; } \
            bf16x8 pf;                                                          \
            __builtin_memcpy(&pf, &pu, 16);                                     \
            _Pragma("unroll")                                                   \
            for (int dt = 0; dt < 2; ++dt) {                                    \
                bf16x8 vf = *(const bf16x8*)(smem + (VB) + voffb[c2 * 2 + dt]); \
                o_acc[dt] = __builtin_amdgcn_mfma_f32_32x32x16_bf16(            \
                    pf, vf, o_acc[dt], 0, 0, 0);                                \
            }                                                                   \
        }                                                                       \
    }

__launch_bounds__(512, 4)
__global__ void attn(const u16* __restrict__ Q, const u16* __restrict__ K,
                     const u16* __restrict__ Vt, float* __restrict__ out) {
    __shared__ __align__(16) char smem[34816];
    // K0 @0, K1 @8192, V0 @16384, V1 @24576; l @33792; o_lds overlay @0
    float* l_lds = (float*)(smem + 33792);
    float* o_lds = (float*)smem;

    const int i = blockIdx.x;
    const int g = i & 7, r_ = i >> 3;
    const int qb = r_ & 15, bh = ((r_ >> 4) << 3) + g;
    const int h_ = bh >> 2, b = bh & 3;

    const int tid = threadIdx.x, w = tid >> 6, lane = tid & 63;
    const int q0 = qb * 128;
    const int lm32 = lane & 31, hi = lane >> 5;
    const int qg = w & 3, hk = w >> 2;
    const int qrow = qg * 32 + lm32;

    const u16* Qb = Q + ((size_t)b * L_SEQ + q0) * DM + h_ * 64;
    const u16* Kb = K + (size_t)b * L_SEQ * DM + h_ * 64;
    const u16* Vb = Vt + ((size_t)b * DM + h_ * 64) * L_SEQ;

    // staging sources (1 slot of 16B per thread) + LDS dest byte offset
    const u16 *pKn, *pVn;
    const int sdb = w * 1024;   // (w*64)*16 bytes, wave-uniform
    {
        int r = tid >> 3, cc = (tid & 7) ^ (r & 7);
        pKn = Kb + (size_t)r * DM + cc * 8;
        pVn = Vb + (size_t)r * L_SEQ + cc * 8;
    }

    // loop-invariant fragment byte offsets
    const int rk = hk * 32 + lm32;
    int koffb[4], voffb[4];
#pragma unroll
    for (int c = 0; c < 4; ++c)
        koffb[c] = rk * 128 + ((2 * c + hi) ^ (rk & 7)) * 16;
#pragma unroll
    for (int c2 = 0; c2 < 2; ++c2)
#pragma unroll
        for (int dt = 0; dt < 2; ++dt) {
            int d = dt * 32 + lm32;
            int kc = hk * 4 + c2 * 2 + hi;
            voffb[c2 * 2 + dt] = d * 128 + (kc ^ (d & 7)) * 16;
        }

    // stage Q (128x64 = 16KB) through K0+K1
#pragma unroll
    for (int j = 0; j < 2; ++j) {
        int s = j * 512 + tid;
        int r = s >> 3, cc = (s & 7) ^ (r & 7);
        lds_load16(Qb + (size_t)r * DM + cc * 8, smem + j * 8192 + sdb);
    }
    __syncthreads();
    bf16x8 qf[4];
#pragma unroll
    for (int c = 0; c < 4; ++c) {
        int slot = (2 * c + hi) ^ (qrow & 7);
        qf[c] = *(const bf16x8*)(smem + qrow * 128 + slot * 16);
    }
    __syncthreads();   // Q reads done; K bufs reusable

    float l_part = 0.f;
    f32x16 o_acc[2];
    o_acc[0] = zero16(); o_acc[1] = zero16();

    // prologue: stage tile 0 into K0/V0
    lds_load16(pKn, smem + 0 + sdb);
    lds_load16(pVn, smem + 16384 + sdb);
    pKn += 64 * DM; pVn += 64;

    for (int kt2 = 0; kt2 < 16; ++kt2) {
        ATTN_BODY(0, 16384, 8192, 24576, true)           // tile 2kt2 (buf0), stage 2kt2+1
        ATTN_BODY(8192, 24576, 0, 16384, (kt2 < 15))     // tile 2kt2+1 (buf1), stage 2kt2+2
    }

    // per-(q, half) row sum
    l_part += __shfl_xor(l_part, 32);

    __syncthreads();   // kv bufs dead; overlay o_lds
    if (hi == 0) l_lds[hk * 128 + qrow] = l_part;
    if (hk == 0) {
#pragma unroll
        for (int dt = 0; dt < 2; ++dt) {
            int d = dt * 32 + lm32;
#pragma unroll
            for (int g2 = 0; g2 < 4; ++g2) {
                f32x4 vq;
#pragma unroll
                for (int r = 0; r < 4; ++r) vq[r] = o_acc[dt][4 * g2 + r];
                *(f32x4*)(o_lds + d * 132 + qg * 32 + 8 * g2 + 4 * hi) = vq;
            }
        }
    }
    __syncthreads();
    if (hk == 1) {
#pragma unroll
        for (int dt = 0; dt < 2; ++dt) {
            int d = dt * 32 + lm32;
#pragma unroll
            for (int g2 = 0; g2 < 4; ++g2) {
                float* ad = o_lds + d * 132 + qg * 32 + 8 * g2 + 4 * hi;
                f32x4 cur = *(f32x4*)ad;
#pragma unroll
                for (int r = 0; r < 4; ++r) cur[r] += o_acc[dt][4 * g2 + r];
                *(f32x4*)ad = cur;
            }
        }
    }
    __syncthreads();
    float* ob = out + ((size_t)b * DM + h_ * 64) * L_SEQ + q0;
#pragma unroll
    for (int p = 0; p < 4; ++p) {
        int id = p * 512 + tid;
        int d = id >> 5, rc = id & 31;
        f32x4 vv = *(const f32x4*)(o_lds + d * 132 + rc * 4);
        f32x4 la = *(const f32x4*)(l_lds + rc * 4);
        f32x4 lb = *(const f32x4*)(l_lds + 128 + rc * 4);
#pragma unroll
        for (int j = 0; j < 4; ++j) vv[j] *= 1.0f / (la[j] + lb[j]);
        *(f32x4*)(ob + (size_t)d * L_SEQ + rc * 4) = vv;
    }
}

extern "C" void kernel_launch(void* const* d_in, const int* in_sizes, int n_in,
                              void* d_out, int out_size, void* d_ws, size_t ws_size,
                              hipStream_t stream) {
    const float* x1 = (const float*)d_in[0];
    const float* x2 = (const float*)d_in[1];
    const float* Wq = (const float*)d_in[2];
    const float* bq = (const float*)d_in[3];
    const float* Wk = (const float*)d_in[4];
    const float* bk = (const float*)d_in[5];
    const float* Wv = (const float*)d_in[6];
    const float* bv = (const float*)d_in[7];
    float* out = (float*)d_out;

    char* ws = (char*)d_ws;
    u16* x1T = (u16*)(ws);
    u16* x2T = (u16*)(ws + 8388608);
    u16* Wall = (u16*)(ws + 16777216);
    u16* Qb  = (u16*)(ws + 18350080);
    u16* Kb  = (u16*)(ws + 26738688);
    u16* Vtb = (u16*)(ws + 35127296);

    prep<<<dim3(16, 4, 9), 256, 0, stream>>>(x1, x2, Wq, Wk, Wv, x1T, Wall);
    proj_gemm<<<dim3(64, 12), 256, 0, stream>>>(x1T, x2T, Wall, bq, bk, bv, Qb, Kb, Vtb);
    attn<<<512, 512, 0, stream>>>(Qb, Kb, Vtb, out);
}